// Round 1
// baseline (927.055 us; speedup 1.0000x reference)
//
#include <hip/hip_runtime.h>
#include <stdint.h>

#define BATCH   32
#define NPRED   25200
#define NCLS    80
#define ROWF    85
#define CONF_T  0.25f
#define IOU_T   0.45f
#define MAX_DET 1000
#define KNMS    4096
#define MAXWH   7680.0f

// ---------------- K1: per-row conf / argmax / flags (coalesced via LDS) ----------------
#define K1_ROWS    128
#define K1_THREADS 256

__global__ __launch_bounds__(K1_THREADS) void k1_rowstats(const float* __restrict__ pred,
                                                          float* __restrict__ conf,
                                                          uint32_t* __restrict__ meta) {
  __shared__ float lds[K1_ROWS * ROWF];  // 128*85 floats = 43520 B
  const int t = threadIdx.x;
  const long rowBase = (long)blockIdx.x * K1_ROWS;
  const float4* src4 = (const float4*)(pred + rowBase * ROWF);  // rowBase*85*4 % 16 == 0
  float4* lds4 = (float4*)lds;
  #pragma unroll
  for (int i = 0; i < 11; ++i) {
    int idx = t + i * K1_THREADS;
    if (idx < (K1_ROWS * ROWF / 4)) lds4[idx] = src4[idx];
  }
  __syncthreads();
  const int row = t >> 1, h = t & 1;
  const float* rp = lds + row * ROWF;
  const float obj = rp[4];
  const int c0 = h * 40;
  float best = rp[5 + c0] * obj;
  int bj = c0;
  for (int c = 1; c < 40; ++c) {
    float v = rp[5 + c0 + c] * obj;
    if (v > best) { best = v; bj = c0 + c; }  // strict > keeps first occurrence
  }
  const float obest = __shfl_xor(best, 1);
  const int ojj = __shfl_xor(bj, 1);
  if (h == 0) {
    if (obest > best) { best = obest; bj = ojj; }  // ties -> lower half (lower class idx)
    const long g = rowBase + row;
    conf[g] = best;
    uint32_t m = (uint32_t)bj;
    if (obj > CONF_T) m |= 0x100u;
    if (obj > CONF_T && best > CONF_T) m |= 0x200u;
    meta[g] = m;
  }
}

// ---------------- K2: per-image compaction + sort + NMS + accumulate ----------------
__global__ __launch_bounds__(1024) void k2_nms(const float* __restrict__ pred,
                                               const float* __restrict__ conf,
                                               const uint32_t* __restrict__ meta,
                                               int* __restrict__ xcRows,
                                               int* __restrict__ validR,
                                               float* __restrict__ out) {
  const int b = blockIdx.x;
  const int t = threadIdx.x;
  const int lane = t & 63;
  const int w = t >> 6;

  const float* P = pred + (size_t)b * NPRED * ROWF;
  const float* C = conf + (size_t)b * NPRED;
  const uint32_t* M = meta + (size_t)b * NPRED;
  int* XC = xcRows + (size_t)b * NPRED;
  int* VR = validR + (size_t)b * NPRED;

  __shared__ unsigned long long keys[KNMS];   // 32 KB; reused as tile suppression matrix
  __shared__ unsigned short qlist[KNMS];      // 8 KB
  __shared__ float sbx1[64], sby1[64], sbx2[64], sby2[64], sbar[64];
  __shared__ unsigned long long keepw[64];
  __shared__ unsigned long long keptword;
  __shared__ int wsum1[16], wsum2[16];
  __shared__ int base1, base2;
  __shared__ float waveacc[16][NCLS];         // 5 KB
  __shared__ unsigned short klist[1024];
  __shared__ int kcount;

  // ---- phase A: stable compaction of xc rows and valid rows ----
  if (t == 0) { base1 = 0; base2 = 0; }
  for (int i = t; i < KNMS; i += 1024) keys[i] = 0ull;
  __syncthreads();

  for (int base = 0; base < NPRED; base += 1024) {
    const int r = base + t;
    bool fx = false, fv = false;
    float cf = 0.f;
    if (r < NPRED) {
      const uint32_t mm = M[r];
      fx = (mm & 0x100u) != 0;
      fv = (mm & 0x200u) != 0;
      cf = C[r];
    }
    const unsigned long long bx = __ballot(fx);
    const unsigned long long bv = __ballot(fv);
    if (lane == 0) { wsum1[w] = __popcll(bx); wsum2[w] = __popcll(bv); }
    __syncthreads();
    int off1 = base1, off2 = base2;
    for (int ww = 0; ww < w; ++ww) { off1 += wsum1[ww]; off2 += wsum2[ww]; }
    const unsigned long long lm = (1ull << lane) - 1ull;
    if (fx) XC[off1 + __popcll(bx & lm)] = r;
    if (fv) {
      const int p2 = off2 + __popcll(bv & lm);
      VR[p2] = r;
      if (p2 < KNMS)
        keys[p2] = ((unsigned long long)__float_as_uint(cf) << 32) | (unsigned)(~(unsigned)p2);
    }
    __syncthreads();
    if (t == 0) {
      int s1 = 0, s2 = 0;
      for (int ww = 0; ww < 16; ++ww) { s1 += wsum1[ww]; s2 += wsum2[ww]; }
      base1 += s1; base2 += s2;
    }
    __syncthreads();
  }
  const int m2 = base2;
  const int m2c = (m2 < KNMS) ? m2 : KNMS;

  // ---- phase B: bitonic sort of keys, DESCENDING (conf bits || ~rank for stable ties) ----
  for (unsigned k = 2; k <= KNMS; k <<= 1) {
    for (unsigned j = k >> 1; j > 0; j >>= 1) {
      __syncthreads();
      for (unsigned m = t; m < KNMS / 2; m += 1024) {
        const unsigned i = 2u * m - (m & (j - 1u));
        const unsigned l = i + j;
        const unsigned long long a = keys[i], c2 = keys[l];
        const bool up = ((i & k) == 0u);
        if ((a < c2) == up) { keys[i] = c2; keys[l] = a; }
      }
    }
  }
  __syncthreads();
  for (int i = t; i < KNMS; i += 1024) qlist[i] = (unsigned short)(~(unsigned)keys[i]);
  __syncthreads();

  // ---- phase C: candidate boxes into registers (thread t owns i = t + 1024*kk) ----
  float bx1[4], by1[4], bx2[4], by2[4], bar[4];
  int aliveBits = 0;
  #pragma unroll
  for (int kk = 0; kk < 4; ++kk) {
    const int i = t + 1024 * kk;
    float x1 = 0.f, y1 = 0.f, x2 = 0.f, y2 = 0.f, ar = 0.f;
    if (i < m2c) {
      const int q = qlist[i];
      const int R = VR[q];
      const float* gp = P + (size_t)R * ROWF;
      const float cx = gp[0], cy = gp[1], wd = gp[2], ht = gp[3];
      const int cj = (int)(M[R] & 0xFFu);
      const float off = (float)cj * MAXWH;
      const float hw = wd * 0.5f, hh = ht * 0.5f;
      x1 = (cx - hw) + off;
      y1 = (cy - hh) + off;
      x2 = (cx + hw) + off;
      y2 = (cy + hh) + off;
      ar = (x2 - x1) * (y2 - y1);
      aliveBits |= (1 << kk);
    }
    bx1[kk] = x1; by1[kk] = y1; bx2[kk] = x2; by2[kk] = y2; bar[kk] = ar;
  }

  const int ntiles = (m2c + 63) >> 6;

  // ---- phase D1: per-tile 64x64 suppression rows (parallel across waves) ----
  // row[l] = { j : IoU(box_l, box_j) > thr && j > l }   (tile-local indices)
  #pragma unroll
  for (int kk = 0; kk < 4; ++kk) {
    const int T = w + 16 * kk;  // tile T lives in wave T&15, slot T>>4
    if (T < ntiles) {
      const float mx1 = bx1[kk], my1 = by1[kk], mx2 = bx2[kk], my2 = by2[kk], mar = bar[kk];
      unsigned long long row = 0ull;
      for (int j = 0; j < 64; ++j) {
        const float ox1 = __shfl(mx1, j), oy1 = __shfl(my1, j);
        const float ox2 = __shfl(mx2, j), oy2 = __shfl(my2, j);
        const float oar = __shfl(mar, j);
        const float iw = fminf(ox2, mx2) - fmaxf(ox1, mx1);
        const float ih = fminf(oy2, my2) - fmaxf(oy1, my1);
        const float inter = fmaxf(iw, 0.f) * fmaxf(ih, 0.f);
        const float iou = inter / ((oar + mar) - inter);  // area_j + area_i - inter
        if ((iou > IOU_T) && (j > lane)) row |= (1ull << j);
      }
      keys[T * 64 + lane] = row;
    }
  }
  __syncthreads();

  // ---- phase D2: serial greedy over tiles, parallel inter-tile suppression ----
  for (int T = 0; T < ntiles; ++T) {
    const int gw = T & 15, gk = T >> 4;
    if (w == gw) {
      float mx1 = 0.f, my1 = 0.f, mx2 = 0.f, my2 = 0.f, mar = 0.f;
      bool myAlive = false;
      #pragma unroll
      for (int kk = 0; kk < 4; ++kk)
        if (kk == gk) {
          mx1 = bx1[kk]; my1 = by1[kk]; mx2 = bx2[kk]; my2 = by2[kk]; mar = bar[kk];
          myAlive = ((aliveBits >> kk) & 1) != 0;
        }
      unsigned long long alive64 = __ballot(myAlive);
      unsigned long long kept = 0ull;
      while (alive64) {
        const int bb = __builtin_ctzll(alive64);
        kept |= (1ull << bb);
        alive64 &= ~(keys[T * 64 + bb] | (1ull << bb));
      }
      const bool keepMine = ((kept >> lane) & 1ull) != 0;
      #pragma unroll
      for (int kk = 0; kk < 4; ++kk)
        if (kk == gk) { if (!keepMine) aliveBits &= ~(1 << kk); }
      sbx1[lane] = mx1; sby1[lane] = my1; sbx2[lane] = mx2; sby2[lane] = my2; sbar[lane] = mar;
      if (lane == 0) keptword = kept;
    }
    __syncthreads();
    const unsigned long long km = keptword;
    const int tEnd = T * 64 + 63;
    if (km) {
      #pragma unroll
      for (int kk = 0; kk < 4; ++kk) {
        const int i = t + 1024 * kk;
        if (((aliveBits >> kk) & 1) && i > tEnd) {
          const float mx1 = bx1[kk], my1 = by1[kk], mx2 = bx2[kk], my2 = by2[kk], mar = bar[kk];
          unsigned long long mloop = km;
          while (mloop) {
            const int bb = __builtin_ctzll(mloop);
            mloop &= mloop - 1ull;
            const float iw = fminf(sbx2[bb], mx2) - fmaxf(sbx1[bb], mx1);
            const float ih = fminf(sby2[bb], my2) - fmaxf(sby1[bb], my1);
            const float inter = fmaxf(iw, 0.f) * fmaxf(ih, 0.f);
            const float iou = inter / ((mar + sbar[bb]) - inter);
            if (iou > IOU_T) { aliveBits &= ~(1 << kk); break; }
          }
        }
      }
    }
    __syncthreads();
  }

  // ---- final keep bitmask over the 4096 candidate slots ----
  #pragma unroll
  for (int kk = 0; kk < 4; ++kk) {
    const unsigned long long kb = __ballot((aliveBits >> kk) & 1);
    if (lane == 0) keepw[kk * 16 + w] = kb;
  }
  __syncthreads();

  // ---- MAX_DET cap: keep only first 1000 kept (in candidate order) ----
  if (t == 0) {
    int running = 0;
    for (int widx = 0; widx < 64; ++widx) {
      unsigned long long word = keepw[widx];
      const int c = __popcll(word);
      if (running + c > MAX_DET) {
        const int allow = MAX_DET - running;
        unsigned long long nw = 0ull;
        for (int a = 0; a < allow; ++a) {
          const int bpos = __builtin_ctzll(word);
          nw |= (1ull << bpos);
          word &= word - 1ull;
        }
        keepw[widx] = nw;
        for (int z = widx + 1; z < 64; ++z) keepw[z] = 0ull;
        break;
      }
      running += c;
    }
  }
  __syncthreads();

  // ---- build compact kept list ----
  if (t < 64) {
    int pre = 0;
    for (int ww = 0; ww < t; ++ww) pre += __popcll(keepw[ww]);
    unsigned long long word = keepw[t];
    while (word) {
      const int bpos = __builtin_ctzll(word);
      word &= word - 1ull;
      klist[pre++] = (unsigned short)(t * 64 + bpos);
    }
    if (t == 63) kcount = pre;
  }
  __syncthreads();
  const int KC = kcount;

  // ---- accumulate: out[b,c] = sum over kept of pred[P_i,5+c] * pred[P_i,4]
  //      (reference quirk: credited row is xcRows[q], NOT validR[q]) ----
  float accA = 0.f, accB = 0.f;
  for (int e = w; e < KC; e += 16) {
    const int i = klist[e];
    const int q = qlist[i];
    const int Prow = XC[q];
    const float* gp = P + (size_t)Prow * ROWF;
    const float obj = gp[4];
    accA += gp[5 + lane] * obj;
    if (lane < 16) accB += gp[5 + 64 + lane] * obj;
  }
  waveacc[w][lane] = accA;
  if (lane < 16) waveacc[w][64 + lane] = accB;
  __syncthreads();
  if (t < NCLS) {
    float s = 0.f;
    for (int ww = 0; ww < 16; ++ww) s += waveacc[ww][t];
    out[b * NCLS + t] = s;
  }
}

extern "C" void kernel_launch(void* const* d_in, const int* in_sizes, int n_in,
                              void* d_out, int out_size, void* d_ws, size_t ws_size,
                              hipStream_t stream) {
  const float* pred = (const float*)d_in[0];
  float* out = (float*)d_out;

  float* conf = (float*)d_ws;
  uint32_t* meta = (uint32_t*)(conf + (size_t)BATCH * NPRED);
  int* xcRows = (int*)(meta + (size_t)BATCH * NPRED);
  int* validR = (int*)(xcRows + (size_t)BATCH * NPRED);

  hipLaunchKernelGGL(k1_rowstats, dim3((BATCH * NPRED) / K1_ROWS), dim3(K1_THREADS), 0, stream,
                     pred, conf, meta);
  hipLaunchKernelGGL(k2_nms, dim3(BATCH), dim3(1024), 0, stream,
                     pred, conf, meta, xcRows, validR, out);
}